// Round 5
// baseline (1932.129 us; speedup 1.0000x reference)
//
#include <hip/hip_runtime.h>
#include <hip/hip_bf16.h>
#include <math.h>

typedef __bf16 bf16;
typedef __bf16 bf16x8 __attribute__((ext_vector_type(8)));
typedef float f32x4 __attribute__((ext_vector_type(4)));

#define DIM 1280
#define SEQ 4096
#define NH 16
#define HD 80
#define HIDDEN 5120
#define FLAG_THRESH 4096

__device__ __forceinline__ f32x4 fz4() { f32x4 v; v.x = 0.f; v.y = 0.f; v.z = 0.f; v.w = 0.f; return v; }

// dtype-dispatched load of external input arrays (fp32 or bf16 decided at runtime)
__device__ __forceinline__ float ldx(const void* p, size_t i, bool f32) {
  if (f32) return ((const float*)p)[i];
  return (float)((const bf16*)p)[i];
}

// ---------------- flag prologue: decide whether external floats are fp32 or bf16
__global__ void zero_flag_k(int* flag) { *flag = 0; }

__global__ __launch_bounds__(256) void sniff_k(const unsigned short* h, int n, int* flag) {
  int i = blockIdx.x * 256 + threadIdx.x;
  int c = 0;
  for (int idx = i; idx < n; idx += 256 * gridDim.x) {
    int e = (h[idx] >> 7) & 0xFF;  // bf16 exponent field
    c += (e >= 0xC8) ? 1 : 0;      // |x| >= 2^73: impossible for sane bf16 data
  }
  #pragma unroll
  for (int o = 32; o; o >>= 1) c += __shfl_down(c, o);
  if ((threadIdx.x & 63) == 0 && c) atomicAdd(flag, c);
}

// ---------------- transpose+convert: in[R][C] -> out[C][R] bf16
__global__ __launch_bounds__(256) void transpose_k(const void* __restrict__ in, bf16* __restrict__ out,
                                                   int R, int C, const int* __restrict__ flag) {
  bool f32 = *flag > FLAG_THRESH;
  __shared__ bf16 tile[32][33];
  int c0 = blockIdx.x * 32, r0 = blockIdx.y * 32;
  int tx = threadIdx.x, ty = threadIdx.y;
  #pragma unroll
  for (int i = 0; i < 4; i++)
    tile[ty + 8 * i][tx] = (bf16)ldx(in, (size_t)(r0 + ty + 8 * i) * C + c0 + tx, f32);
  __syncthreads();
  #pragma unroll
  for (int i = 0; i < 4; i++)
    out[(size_t)(c0 + ty + 8 * i) * R + r0 + tx] = tile[tx][ty + 8 * i];
}

// ---------------- layernorm over 1280 cols, one block per row, out bf16
__global__ __launch_bounds__(256) void ln_k(const void* __restrict__ x, const void* __restrict__ sc,
                                            const void* __restrict__ bi, bf16* __restrict__ out,
                                            const int* __restrict__ flag, int force_f32) {
  bool pf32 = *flag > FLAG_THRESH;
  bool xf32 = force_f32 || pf32;
  int row = blockIdx.x, t = threadIdx.x;
  float v[5];
  float s = 0.f, sq = 0.f;
  #pragma unroll
  for (int i = 0; i < 5; i++) {
    v[i] = ldx(x, (size_t)row * DIM + i * 256 + t, xf32);
    s += v[i]; sq += v[i] * v[i];
  }
  #pragma unroll
  for (int o = 32; o; o >>= 1) { s += __shfl_down(s, o); sq += __shfl_down(sq, o); }
  __shared__ float rs[4], rq[4];
  if ((t & 63) == 0) { rs[t >> 6] = s; rq[t >> 6] = sq; }
  __syncthreads();
  s = rs[0] + rs[1] + rs[2] + rs[3];
  sq = rq[0] + rq[1] + rq[2] + rq[3];
  float mean = s * (1.f / DIM);
  float var = sq * (1.f / DIM) - mean * mean;
  float rstd = rsqrtf(fmaxf(var, 0.f) + 1e-6f);
  #pragma unroll
  for (int i = 0; i < 5; i++) {
    int c = i * 256 + t;
    out[(size_t)row * DIM + c] = (bf16)((v[i] - mean) * rstd * ldx(sc, c, pf32) + ldx(bi, c, pf32));
  }
}

// ---------------- GEMM  C[M,N] = A[M,K] * Bt[N,K]^T  (128x128 tile, BK=32, plain LDS staging)
// MODE 0: out bf16 = acc+bias
// MODE 1: out f32  = acc+bias+res_ext(flag dtype)
// MODE 2: out bf16 = quickgelu(acc+bias)
// MODE 3: out f32  = acc+bias+res_f32      <-- final output is fp32 (reference output dtype)
template <int MODE>
__global__ __launch_bounds__(256) void gemm_bt(const bf16* __restrict__ A, const bf16* __restrict__ Bt,
                                               const void* __restrict__ bias, const void* __restrict__ res,
                                               void* __restrict__ out, int M, int N, int K,
                                               const int* __restrict__ flag) {
  bool pf32 = *flag > FLAG_THRESH;
  __shared__ bf16 As[128 * 32];
  __shared__ bf16 Bs[128 * 32];
  int tid = threadIdx.x;
  int lane = tid & 63, wv = tid >> 6;
  int quad = lane >> 4, l15 = lane & 15;
  int m0 = blockIdx.y * 128, n0 = blockIdx.x * 128;
  int wm = (wv & 1) * 64, wn = (wv >> 1) * 64;
  const bf16* Ag = A + (size_t)m0 * K;
  const bf16* Bg = Bt + (size_t)n0 * K;
  int r0 = tid >> 2, c0 = (tid & 3) * 8;
  int r1 = r0 + 64;
  f32x4 acc[4][4];
  #pragma unroll
  for (int i = 0; i < 4; i++)
    #pragma unroll
    for (int j = 0; j < 4; j++) acc[i][j] = fz4();

  for (int k0 = 0; k0 < K; k0 += 32) {
    bf16x8 a0 = *(const bf16x8*)&Ag[(size_t)r0 * K + k0 + c0];
    bf16x8 a1 = *(const bf16x8*)&Ag[(size_t)r1 * K + k0 + c0];
    bf16x8 b0 = *(const bf16x8*)&Bg[(size_t)r0 * K + k0 + c0];
    bf16x8 b1 = *(const bf16x8*)&Bg[(size_t)r1 * K + k0 + c0];
    *(bf16x8*)&As[(size_t)r0 * 32 + c0] = a0;
    *(bf16x8*)&As[(size_t)r1 * 32 + c0] = a1;
    *(bf16x8*)&Bs[(size_t)r0 * 32 + c0] = b0;
    *(bf16x8*)&Bs[(size_t)r1 * 32 + c0] = b1;
    __syncthreads();
    bf16x8 af[4], bfr[4];
    #pragma unroll
    for (int tm = 0; tm < 4; tm++) af[tm] = *(const bf16x8*)&As[(wm + tm * 16 + l15) * 32 + quad * 8];
    #pragma unroll
    for (int tn = 0; tn < 4; tn++) bfr[tn] = *(const bf16x8*)&Bs[(wn + tn * 16 + l15) * 32 + quad * 8];
    #pragma unroll
    for (int tm = 0; tm < 4; tm++)
      #pragma unroll
      for (int tn = 0; tn < 4; tn++)
        acc[tm][tn] = __builtin_amdgcn_mfma_f32_16x16x32_bf16(af[tm], bfr[tn], acc[tm][tn], 0, 0, 0);
    __syncthreads();
  }

  #pragma unroll
  for (int tm = 0; tm < 4; tm++) {
    #pragma unroll
    for (int tn = 0; tn < 4; tn++) {
      #pragma unroll
      for (int r = 0; r < 4; r++) {
        int row = m0 + wm + tm * 16 + quad * 4 + r;
        int col = n0 + wn + tn * 16 + l15;
        size_t idx = (size_t)row * N + col;
        float vv = acc[tm][tn][r] + ldx(bias, col, pf32);
        if constexpr (MODE == 0) ((bf16*)out)[idx] = (bf16)vv;
        if constexpr (MODE == 1) ((float*)out)[idx] = vv + ldx(res, idx, pf32);
        if constexpr (MODE == 2) ((bf16*)out)[idx] = (bf16)(vv / (1.f + expf(-1.702f * vv)));
        if constexpr (MODE == 3) ((float*)out)[idx] = vv + ((const float*)res)[idx];
      }
    }
  }
}

// ---------------- RoPE IN-PLACE on qkv [seq][3840]; q scaled by 1/sqrt(80); v untouched
__global__ __launch_bounds__(256) void rope_k(bf16* __restrict__ qkv, const void* __restrict__ rot,
                                              const int* __restrict__ flag) {
  bool pf32 = *flag > FLAG_THRESH;
  int idx = blockIdx.x * 256 + threadIdx.x;  // over SEQ*NH*40
  int d = idx % 40;
  int t = idx / 40;
  int head = t & 15;
  int seq = t >> 4;
  float f1 = ldx(rot, (size_t)seq * 40 + (d >> 1), pf32);
  float f2 = ldx(rot, (size_t)seq * 40 + (d >> 1) + 20, pf32);
  float c1 = cosf(f1), s1 = sinf(f1), c2 = cosf(f2), s2 = sinf(f2);
  const float scq = 0.11180339887498949f;  // 1/sqrt(80)
  size_t base = (size_t)seq * (3 * DIM) + head * HD + d;
  float x1 = (float)qkv[base], x2 = (float)qkv[base + 40];
  qkv[base] = (bf16)((x1 * c1 - x2 * s1) * scq);
  qkv[base + 40] = (bf16)((x2 * c2 + x1 * s2) * scq);
  x1 = (float)qkv[base + DIM]; x2 = (float)qkv[base + DIM + 40];
  qkv[base + DIM] = (bf16)(x1 * c1 - x2 * s1);
  qkv[base + DIM + 40] = (bf16)(x2 * c2 + x1 * s2);
}

// ---------------- scalar flash attention (trivially correct); reads strided qkv [seq][3840]
// one block = (64 q-rows, head, seg); one thread = one q-row; all softmax state thread-local
__global__ __launch_bounds__(64) void attn_scalar_k(const bf16* __restrict__ qkv, const int* __restrict__ cu,
                                                    bf16* __restrict__ out) {
  __shared__ bf16 Ks[64 * 80];
  __shared__ bf16 Vs[64 * 80];
  __shared__ float Ss[64][65];  // +1 pad vs 64-way fp32 bank conflict
  int tid = threadIdx.x;
  int qt = blockIdx.x, head = blockIdx.y, seg = blockIdx.z;
  int s0 = cu[seg], s1 = cu[seg + 1];
  int q0 = s0 + qt * 64;
  if (q0 >= s1) return;
  const bf16* qh = qkv + head * HD;               // col offset of this head's q
  const bf16* kh = qkv + DIM + head * HD;         // k
  const bf16* vh = qkv + 2 * DIM + head * HD;     // v
  int myrow = q0 + tid;
  bool rowok = myrow < s1;
  float qr[80];
  #pragma unroll
  for (int c = 0; c < 10; c++) {
    bf16x8 qq;
    if (rowok) qq = *(const bf16x8*)&qh[(size_t)myrow * (3 * DIM) + c * 8];
    #pragma unroll
    for (int e = 0; e < 8; e++) qr[c * 8 + e] = rowok ? (float)qq[e] : 0.f;
  }
  float m = -1e30f, l = 0.f;
  float oacc[80];
  #pragma unroll
  for (int d = 0; d < 80; d++) oacc[d] = 0.f;

  for (int kt = s0; kt < s1; kt += 64) {
    int kn = min(64, s1 - kt);
    __syncthreads();
    if (tid < kn) {
      #pragma unroll
      for (int c = 0; c < 10; c++) {
        *(bf16x8*)&Ks[tid * 80 + c * 8] = *(const bf16x8*)&kh[(size_t)(kt + tid) * (3 * DIM) + c * 8];
        *(bf16x8*)&Vs[tid * 80 + c * 8] = *(const bf16x8*)&vh[(size_t)(kt + tid) * (3 * DIM) + c * 8];
      }
    }
    __syncthreads();
    float mx = m;
    #pragma unroll 1
    for (int j = 0; j < kn; j++) {
      float acc = 0.f;
      #pragma unroll
      for (int c = 0; c < 10; c++) {
        bf16x8 kk = *(const bf16x8*)&Ks[j * 80 + c * 8];
        #pragma unroll
        for (int e = 0; e < 8; e++) acc += qr[c * 8 + e] * (float)kk[e];
      }
      Ss[tid][j] = acc;
      mx = fmaxf(mx, acc);
    }
    float alpha = expf(m - mx);
    l *= alpha;
    #pragma unroll
    for (int d = 0; d < 80; d++) oacc[d] *= alpha;
    #pragma unroll 1
    for (int j = 0; j < kn; j++) {
      float p = expf(Ss[tid][j] - mx);
      l += p;
      #pragma unroll
      for (int c = 0; c < 10; c++) {
        bf16x8 vv = *(const bf16x8*)&Vs[j * 80 + c * 8];
        #pragma unroll
        for (int e = 0; e < 8; e++) oacc[c * 8 + e] += p * (float)vv[e];
      }
    }
    m = mx;
  }
  if (rowok) {
    #pragma unroll
    for (int d = 0; d < 80; d++)
      out[(size_t)myrow * DIM + head * HD + d] = (bf16)(oacc[d] / l);
  }
}

// ---------------- compact aliased workspace layout (total 55,050,496 B = 52.5 MB)
#define FLAG_OFF 0UL
#define WT_OFF 256UL
#define SLOTA_OFF 13107456UL
#define SLOTB_OFF 23593216UL
#define FC1_OFF 44564736UL
#define WS_NEEDED 55050496UL

extern "C" void kernel_launch(void* const* d_in, const int* in_sizes, int n_in,
                              void* d_out, int out_size, void* d_ws, size_t ws_size,
                              hipStream_t stream) {
  const void* hidden = d_in[0];
  const void* rot    = d_in[1];
  const int*  cu     = (const int*)d_in[2];
  const void* w_qkv  = d_in[3];
  const void* b_qkv  = d_in[4];
  const void* w_proj = d_in[5];
  const void* b_proj = d_in[6];
  const void* w_fc1  = d_in[7];
  const void* b_fc1  = d_in[8];
  const void* w_fc2  = d_in[9];
  const void* b_fc2  = d_in[10];
  const void* ln1s   = d_in[11];
  const void* ln1b   = d_in[12];
  const void* ln2s   = d_in[13];
  const void* ln2b   = d_in[14];

  char* ws = (char*)d_ws;
  int* flag   = (int*)(ws + FLAG_OFF);
  bf16* wT    = (bf16*)(ws + WT_OFF);
  bf16* slotA = (bf16*)(ws + SLOTA_OFF);   // ln_bf / ao
  bf16* qkv   = (bf16*)(ws + SLOTB_OFF);   // [4096][3840]
  float* h1   = (float*)(ws + SLOTB_OFF);  // [4096][1280] fp32 (after qkv is dead)
  bf16* fc1o  = (bf16*)(ws + FC1_OFF);     // [1024][5120] chunk

  zero_flag_k<<<1, 1, 0, stream>>>(flag);
  sniff_k<<<256, 256, 0, stream>>>((const unsigned short*)hidden, SEQ * DIM, flag);

  dim3 tb(32, 8);
  // --- attention path ---
  transpose_k<<<dim3(120, 40), tb, 0, stream>>>(w_qkv, wT, 1280, 3840, flag);
  ln_k<<<SEQ, 256, 0, stream>>>(hidden, ln1s, ln1b, slotA, flag, 0);
  gemm_bt<0><<<dim3(30, 32), 256, 0, stream>>>(slotA, wT, b_qkv, nullptr, qkv, SEQ, 3 * DIM, DIM, flag);
  rope_k<<<10240, 256, 0, stream>>>(qkv, rot, flag);
  attn_scalar_k<<<dim3(16, NH, 4), 64, 0, stream>>>(qkv, cu, slotA);  // ao -> slotA (qkv read-only here)
  transpose_k<<<dim3(40, 40), tb, 0, stream>>>(w_proj, wT, 1280, 1280, flag);
  gemm_bt<1><<<dim3(10, 32), 256, 0, stream>>>(slotA, wT, b_proj, hidden, h1, SEQ, DIM, DIM, flag);
  // --- MLP path (4 row-chunks of 1024; wT flip-flops fc1T/fc2T) ---
  ln_k<<<SEQ, 256, 0, stream>>>(h1, ln2s, ln2b, slotA, flag, 1);
  for (int c = 0; c < 4; c++) {
    bf16* lnc = slotA + (size_t)c * 1024 * DIM;
    float* h1c = h1 + (size_t)c * 1024 * DIM;
    float* outc = (float*)d_out + (size_t)c * 1024 * DIM;
    transpose_k<<<dim3(160, 40), tb, 0, stream>>>(w_fc1, wT, 1280, 5120, flag);
    gemm_bt<2><<<dim3(40, 8), 256, 0, stream>>>(lnc, wT, b_fc1, nullptr, fc1o, 1024, HIDDEN, DIM, flag);
    transpose_k<<<dim3(40, 160), tb, 0, stream>>>(w_fc2, wT, 5120, 1280, flag);
    gemm_bt<3><<<dim3(10, 8), 256, 0, stream>>>(fc1o, wT, b_fc2, h1c, outc, 1024, DIM, HIDDEN, flag);
  }
}

// Round 6
// 777.376 us; speedup vs baseline: 2.4855x; 2.4855x over previous
//
#include <hip/hip_runtime.h>
#include <hip/hip_bf16.h>
#include <math.h>

typedef __bf16 bf16;
typedef __bf16 bf16x8 __attribute__((ext_vector_type(8)));
typedef float f32x4 __attribute__((ext_vector_type(4)));

#define DIM 1280
#define SEQ 4096
#define NH 16
#define HD 80
#define HIDDEN 5120
#define FLAG_THRESH 4096

__device__ __forceinline__ void gl_lds16(const bf16* g, bf16* l) {
  __builtin_amdgcn_global_load_lds((const __attribute__((address_space(1))) void*)g,
                                   (__attribute__((address_space(3))) void*)l, 16, 0, 0);
}

__device__ __forceinline__ f32x4 fz4() { f32x4 v; v.x = 0.f; v.y = 0.f; v.z = 0.f; v.w = 0.f; return v; }

// dtype-dispatched load of external input arrays (fp32 or bf16 decided at runtime)
__device__ __forceinline__ float ldx(const void* p, size_t i, bool f32) {
  if (f32) return ((const float*)p)[i];
  return (float)((const bf16*)p)[i];
}

// ---------------- flag prologue
__global__ void zero_flag_k(int* flag) { *flag = 0; }

__global__ __launch_bounds__(256) void sniff_k(const unsigned short* h, int n, int* flag) {
  int i = blockIdx.x * 256 + threadIdx.x;
  int c = 0;
  for (int idx = i; idx < n; idx += 256 * gridDim.x) {
    int e = (h[idx] >> 7) & 0xFF;
    c += (e >= 0xC8) ? 1 : 0;
  }
  #pragma unroll
  for (int o = 32; o; o >>= 1) c += __shfl_down(c, o);
  if ((threadIdx.x & 63) == 0 && c) atomicAdd(flag, c);
}

// ---------------- transpose+convert: in[R][C] -> out[C][R] bf16
__global__ __launch_bounds__(256) void transpose_k(const void* __restrict__ in, bf16* __restrict__ out,
                                                   int R, int C, const int* __restrict__ flag) {
  bool f32 = *flag > FLAG_THRESH;
  __shared__ bf16 tile[32][33];
  int c0 = blockIdx.x * 32, r0 = blockIdx.y * 32;
  int tx = threadIdx.x, ty = threadIdx.y;
  #pragma unroll
  for (int i = 0; i < 4; i++)
    tile[ty + 8 * i][tx] = (bf16)ldx(in, (size_t)(r0 + ty + 8 * i) * C + c0 + tx, f32);
  __syncthreads();
  #pragma unroll
  for (int i = 0; i < 4; i++)
    out[(size_t)(c0 + ty + 8 * i) * R + r0 + tx] = tile[tx][ty + 8 * i];
}

// ---------------- layernorm over 1280 cols, one block per row, out bf16
__global__ __launch_bounds__(256) void ln_k(const void* __restrict__ x, const void* __restrict__ sc,
                                            const void* __restrict__ bi, bf16* __restrict__ out,
                                            const int* __restrict__ flag, int force_f32) {
  bool pf32 = *flag > FLAG_THRESH;
  bool xf32 = force_f32 || pf32;
  int row = blockIdx.x, t = threadIdx.x;
  float v[5];
  float s = 0.f, sq = 0.f;
  #pragma unroll
  for (int i = 0; i < 5; i++) {
    v[i] = ldx(x, (size_t)row * DIM + i * 256 + t, xf32);
    s += v[i]; sq += v[i] * v[i];
  }
  #pragma unroll
  for (int o = 32; o; o >>= 1) { s += __shfl_down(s, o); sq += __shfl_down(sq, o); }
  __shared__ float rs[4], rq[4];
  if ((t & 63) == 0) { rs[t >> 6] = s; rq[t >> 6] = sq; }
  __syncthreads();
  s = rs[0] + rs[1] + rs[2] + rs[3];
  sq = rq[0] + rq[1] + rq[2] + rq[3];
  float mean = s * (1.f / DIM);
  float var = sq * (1.f / DIM) - mean * mean;
  float rstd = rsqrtf(fmaxf(var, 0.f) + 1e-6f);
  #pragma unroll
  for (int i = 0; i < 5; i++) {
    int c = i * 256 + t;
    out[(size_t)row * DIM + c] = (bf16)((v[i] - mean) * rstd * ldx(sc, c, pf32) + ldx(bi, c, pf32));
  }
}

// ---------------- GEMM  C[M,N] = A[M,K] * Bt[N,K]^T  (m97: 128x128 tile, BK=32, global_load_lds)
// MODE 0: out bf16 = acc+bias
// MODE 1: out f32  = acc+bias+res_ext(flag dtype)
// MODE 2: out bf16 = quickgelu(acc+bias)
// MODE 3: out f32  = acc+bias+res_f32
template <int MODE>
__global__ __launch_bounds__(256) void gemm_bt(const bf16* __restrict__ A, const bf16* __restrict__ Bt,
                                               const void* __restrict__ bias, const void* __restrict__ res,
                                               void* __restrict__ out, int M, int N, int K,
                                               const int* __restrict__ flag) {
  bool pf32 = *flag > FLAG_THRESH;
  __shared__ bf16 As[128 * 32];
  __shared__ bf16 Bs[128 * 32];
  int tid = threadIdx.x;
  int lane = tid & 63, wv = tid >> 6;
  int quad = lane >> 4, l15 = lane & 15;
  int m0 = blockIdx.y * 128, n0 = blockIdx.x * 128;
  int wm = (wv & 1) * 64, wn = (wv >> 1) * 64;
  const bf16* Ag = A + (size_t)m0 * K;
  const bf16* Bg = Bt + (size_t)n0 * K;
  int r0 = tid >> 2, c0 = (tid & 3) * 8;
  int r1 = r0 + 64;
  f32x4 acc[4][4];
  #pragma unroll
  for (int i = 0; i < 4; i++)
    #pragma unroll
    for (int j = 0; j < 4; j++) acc[i][j] = fz4();

  for (int k0 = 0; k0 < K; k0 += 32) {
    gl_lds16(Ag + (size_t)r0 * K + k0 + c0, &As[tid * 8]);
    gl_lds16(Ag + (size_t)r1 * K + k0 + c0, &As[(tid + 256) * 8]);
    gl_lds16(Bg + (size_t)r0 * K + k0 + c0, &Bs[tid * 8]);
    gl_lds16(Bg + (size_t)r1 * K + k0 + c0, &Bs[(tid + 256) * 8]);
    __syncthreads();
    bf16x8 af[4], bfr[4];
    #pragma unroll
    for (int tm = 0; tm < 4; tm++) af[tm] = *(const bf16x8*)&As[(wm + tm * 16 + l15) * 32 + quad * 8];
    #pragma unroll
    for (int tn = 0; tn < 4; tn++) bfr[tn] = *(const bf16x8*)&Bs[(wn + tn * 16 + l15) * 32 + quad * 8];
    #pragma unroll
    for (int tm = 0; tm < 4; tm++)
      #pragma unroll
      for (int tn = 0; tn < 4; tn++)
        acc[tm][tn] = __builtin_amdgcn_mfma_f32_16x16x32_bf16(af[tm], bfr[tn], acc[tm][tn], 0, 0, 0);
    __syncthreads();
  }

  #pragma unroll
  for (int tm = 0; tm < 4; tm++) {
    #pragma unroll
    for (int tn = 0; tn < 4; tn++) {
      #pragma unroll
      for (int r = 0; r < 4; r++) {
        int row = m0 + wm + tm * 16 + quad * 4 + r;
        int col = n0 + wn + tn * 16 + l15;
        size_t idx = (size_t)row * N + col;
        float vv = acc[tm][tn][r] + ldx(bias, col, pf32);
        if constexpr (MODE == 0) ((bf16*)out)[idx] = (bf16)vv;
        if constexpr (MODE == 1) ((float*)out)[idx] = vv + ldx(res, idx, pf32);
        if constexpr (MODE == 2) ((bf16*)out)[idx] = (bf16)(vv / (1.f + expf(-1.702f * vv)));
        if constexpr (MODE == 3) ((float*)out)[idx] = vv + ((const float*)res)[idx];
      }
    }
  }
}

// ---------------- RoPE IN-PLACE on qkv [seq][3840]; q scaled by 1/sqrt(80); v untouched
__global__ __launch_bounds__(256) void rope_k(bf16* __restrict__ qkv, const void* __restrict__ rot,
                                              const int* __restrict__ flag) {
  bool pf32 = *flag > FLAG_THRESH;
  int idx = blockIdx.x * 256 + threadIdx.x;
  int d = idx % 40;
  int t = idx / 40;
  int head = t & 15;
  int seq = t >> 4;
  float f1 = ldx(rot, (size_t)seq * 40 + (d >> 1), pf32);
  float f2 = ldx(rot, (size_t)seq * 40 + (d >> 1) + 20, pf32);
  float c1 = cosf(f1), s1 = sinf(f1), c2 = cosf(f2), s2 = sinf(f2);
  const float scq = 0.11180339887498949f;
  size_t base = (size_t)seq * (3 * DIM) + head * HD + d;
  float x1 = (float)qkv[base], x2 = (float)qkv[base + 40];
  qkv[base] = (bf16)((x1 * c1 - x2 * s1) * scq);
  qkv[base + 40] = (bf16)((x2 * c2 + x1 * s2) * scq);
  x1 = (float)qkv[base + DIM]; x2 = (float)qkv[base + DIM + 40];
  qkv[base + DIM] = (bf16)(x1 * c1 - x2 * s1);
  qkv[base + DIM + 40] = (bf16)(x2 * c2 + x1 * s2);
}

// ---------------- MFMA flash attention: one block per (q-tile 64, head, segment)
// reads strided qkv [seq][3840]; per-wave 16 q-rows; K-dim padded 80->96
__global__ __launch_bounds__(256) void attn_k(const bf16* __restrict__ qkv, const int* __restrict__ cu,
                                              bf16* __restrict__ out) {
  __shared__ bf16 Qs[64 * 96];
  __shared__ bf16 Ks[64 * 96];
  __shared__ bf16 Vt[80 * 64];
  __shared__ bf16 Ps[4][16 * 64];
  int tid = threadIdx.x, lane = tid & 63, wv = tid >> 6;
  int quad = lane >> 4, l15 = lane & 15;
  int qt = blockIdx.x, head = blockIdx.y, seg = blockIdx.z;
  int s0 = cu[seg], s1 = cu[seg + 1];
  int q0 = s0 + qt * 64;
  if (q0 >= s1) return;
  const bf16* qh = qkv + head * HD;
  const bf16* kh = qkv + DIM + head * HD;
  const bf16* vh = qkv + 2 * DIM + head * HD;
  const int RS = 3 * DIM;  // row stride in qkv
  uint4 z4; z4.x = 0; z4.y = 0; z4.z = 0; z4.w = 0;
  for (int i = tid; i < 128; i += 256) {
    int r = i >> 1, c = i & 1;
    *(uint4*)&Qs[r * 96 + 80 + c * 8] = z4;
    *(uint4*)&Ks[r * 96 + 80 + c * 8] = z4;
  }
  for (int i = tid; i < 640; i += 256) {
    int r = i / 10, c = i % 10;
    *(bf16x8*)&Qs[r * 96 + c * 8] = *(const bf16x8*)&qh[(size_t)(q0 + r) * RS + c * 8];
  }
  float m_r[4], l_r[4];
  f32x4 oacc[5];
  #pragma unroll
  for (int r = 0; r < 4; r++) { m_r[r] = -1e30f; l_r[r] = 0.f; }
  #pragma unroll
  for (int nt = 0; nt < 5; nt++) oacc[nt] = fz4();

  for (int kt = s0; kt < s1; kt += 64) {
    __syncthreads();
    for (int i = tid; i < 640; i += 256) {
      int r = i / 10, c = i % 10;
      *(bf16x8*)&Ks[r * 96 + c * 8] = *(const bf16x8*)&kh[(size_t)(kt + r) * RS + c * 8];
      bf16x8 vv = *(const bf16x8*)&vh[(size_t)(kt + r) * RS + c * 8];
      #pragma unroll
      for (int j = 0; j < 8; j++) Vt[(c * 8 + j) * 64 + r] = vv[j];
    }
    __syncthreads();
    f32x4 sacc[4];
    #pragma unroll
    for (int j = 0; j < 4; j++) sacc[j] = fz4();
    #pragma unroll
    for (int ks = 0; ks < 3; ks++) {
      bf16x8 aq = *(const bf16x8*)&Qs[(wv * 16 + l15) * 96 + ks * 32 + quad * 8];
      #pragma unroll
      for (int j = 0; j < 4; j++) {
        bf16x8 bk = *(const bf16x8*)&Ks[(j * 16 + l15) * 96 + ks * 32 + quad * 8];
        sacc[j] = __builtin_amdgcn_mfma_f32_16x16x32_bf16(aq, bk, sacc[j], 0, 0, 0);
      }
    }
    #pragma unroll
    for (int r = 0; r < 4; r++) {
      float mx = fmaxf(fmaxf(sacc[0][r], sacc[1][r]), fmaxf(sacc[2][r], sacc[3][r]));
      #pragma unroll
      for (int o = 8; o; o >>= 1) mx = fmaxf(mx, __shfl_xor(mx, o));
      float mnew = fmaxf(m_r[r], mx);
      float alpha = expf(m_r[r] - mnew);
      float psum = 0.f;
      #pragma unroll
      for (int j = 0; j < 4; j++) {
        float p = expf(sacc[j][r] - mnew);
        psum += p;
        Ps[wv][(quad * 4 + r) * 64 + j * 16 + l15] = (bf16)p;
      }
      #pragma unroll
      for (int o = 8; o; o >>= 1) psum += __shfl_xor(psum, o);
      l_r[r] = l_r[r] * alpha + psum;
      m_r[r] = mnew;
      #pragma unroll
      for (int nt = 0; nt < 5; nt++) oacc[nt][r] *= alpha;
    }
    __syncthreads();
    #pragma unroll
    for (int ks = 0; ks < 2; ks++) {
      bf16x8 ap = *(const bf16x8*)&Ps[wv][l15 * 64 + ks * 32 + quad * 8];
      #pragma unroll
      for (int nt = 0; nt < 5; nt++) {
        bf16x8 bv = *(const bf16x8*)&Vt[(nt * 16 + l15) * 64 + ks * 32 + quad * 8];
        oacc[nt] = __builtin_amdgcn_mfma_f32_16x16x32_bf16(ap, bv, oacc[nt], 0, 0, 0);
      }
    }
  }
  #pragma unroll
  for (int nt = 0; nt < 5; nt++) {
    #pragma unroll
    for (int r = 0; r < 4; r++) {
      int row = q0 + wv * 16 + quad * 4 + r;
      int d = nt * 16 + l15;
      out[(size_t)row * DIM + head * HD + d] = (bf16)(oacc[nt][r] / l_r[r]);
    }
  }
}

// ---------------- workspace layout (total 154,665,216 B; proven ws_size >= 186 MB in r1-3)
#define FLAG_OFF 0UL
#define QKVT_OFF 256UL
#define PROJT_OFF 9830656UL
#define FC1T_OFF 13107456UL
#define FC2T_OFF 26214656UL
#define LN_OFF 39321856UL
#define QKV_OFF 49807616UL
#define AO_OFF 81264896UL
#define H1_OFF 91750656UL
#define FC1O_OFF 112722176UL

extern "C" void kernel_launch(void* const* d_in, const int* in_sizes, int n_in,
                              void* d_out, int out_size, void* d_ws, size_t ws_size,
                              hipStream_t stream) {
  const void* hidden = d_in[0];
  const void* rot    = d_in[1];
  const int*  cu     = (const int*)d_in[2];
  const void* w_qkv  = d_in[3];
  const void* b_qkv  = d_in[4];
  const void* w_proj = d_in[5];
  const void* b_proj = d_in[6];
  const void* w_fc1  = d_in[7];
  const void* b_fc1  = d_in[8];
  const void* w_fc2  = d_in[9];
  const void* b_fc2  = d_in[10];
  const void* ln1s   = d_in[11];
  const void* ln1b   = d_in[12];
  const void* ln2s   = d_in[13];
  const void* ln2b   = d_in[14];

  char* ws = (char*)d_ws;
  int* flag   = (int*)(ws + FLAG_OFF);
  bf16* qkvT  = (bf16*)(ws + QKVT_OFF);
  bf16* projT = (bf16*)(ws + PROJT_OFF);
  bf16* fc1T  = (bf16*)(ws + FC1T_OFF);
  bf16* fc2T  = (bf16*)(ws + FC2T_OFF);
  bf16* ln_bf = (bf16*)(ws + LN_OFF);
  bf16* qkv   = (bf16*)(ws + QKV_OFF);
  bf16* ao    = (bf16*)(ws + AO_OFF);
  float* h1   = (float*)(ws + H1_OFF);
  bf16* fc1o  = (bf16*)(ws + FC1O_OFF);

  zero_flag_k<<<1, 1, 0, stream>>>(flag);
  sniff_k<<<256, 256, 0, stream>>>((const unsigned short*)hidden, SEQ * DIM, flag);

  dim3 tb(32, 8);
  transpose_k<<<dim3(120, 40), tb, 0, stream>>>(w_qkv, qkvT, 1280, 3840, flag);
  transpose_k<<<dim3(40, 40), tb, 0, stream>>>(w_proj, projT, 1280, 1280, flag);
  transpose_k<<<dim3(160, 40), tb, 0, stream>>>(w_fc1, fc1T, 1280, 5120, flag);
  transpose_k<<<dim3(40, 160), tb, 0, stream>>>(w_fc2, fc2T, 5120, 1280, flag);

  ln_k<<<SEQ, 256, 0, stream>>>(hidden, ln1s, ln1b, ln_bf, flag, 0);
  gemm_bt<0><<<dim3(30, 32), 256, 0, stream>>>(ln_bf, qkvT, b_qkv, nullptr, qkv, SEQ, 3 * DIM, DIM, flag);
  rope_k<<<10240, 256, 0, stream>>>(qkv, rot, flag);
  attn_k<<<dim3(16, NH, 4), 256, 0, stream>>>(qkv, cu, ao);
  gemm_bt<1><<<dim3(10, 32), 256, 0, stream>>>(ao, projT, b_proj, hidden, h1, SEQ, DIM, DIM, flag);
  ln_k<<<SEQ, 256, 0, stream>>>(h1, ln2s, ln2b, ln_bf, flag, 1);
  gemm_bt<2><<<dim3(40, 32), 256, 0, stream>>>(ln_bf, fc1T, b_fc1, nullptr, fc1o, SEQ, HIDDEN, DIM, flag);
  gemm_bt<3><<<dim3(10, 32), 256, 0, stream>>>(fc1o, fc2T, b_fc2, h1, d_out, SEQ, DIM, HIDDEN, flag);
}

// Round 7
// 732.796 us; speedup vs baseline: 2.6367x; 1.0608x over previous
//
#include <hip/hip_runtime.h>
#include <hip/hip_bf16.h>
#include <math.h>

typedef __bf16 bf16;
typedef __bf16 bf16x8 __attribute__((ext_vector_type(8)));
typedef float f32x4 __attribute__((ext_vector_type(4)));

#define DIM 1280
#define SEQ 4096
#define NH 16
#define HD 80
#define HIDDEN 5120
#define FLAG_THRESH 4096

__device__ __forceinline__ void gl_lds16(const bf16* g, bf16* l) {
  __builtin_amdgcn_global_load_lds((const __attribute__((address_space(1))) void*)g,
                                   (__attribute__((address_space(3))) void*)l, 16, 0, 0);
}

__device__ __forceinline__ f32x4 fz4() { f32x4 v; v.x = 0.f; v.y = 0.f; v.z = 0.f; v.w = 0.f; return v; }

__device__ __forceinline__ float ldx(const void* p, size_t i, bool f32) {
  if (f32) return ((const float*)p)[i];
  return (float)((const bf16*)p)[i];
}

// ---------------- flag prologue
__global__ void zero_flag_k(int* flag) { *flag = 0; }

__global__ __launch_bounds__(256) void sniff_k(const unsigned short* h, int n, int* flag) {
  int i = blockIdx.x * 256 + threadIdx.x;
  int c = 0;
  for (int idx = i; idx < n; idx += 256 * gridDim.x) {
    int e = (h[idx] >> 7) & 0xFF;
    c += (e >= 0xC8) ? 1 : 0;
  }
  #pragma unroll
  for (int o = 32; o; o >>= 1) c += __shfl_down(c, o);
  if ((threadIdx.x & 63) == 0 && c) atomicAdd(flag, c);
}

// ---------------- transpose+convert: in[R][C] -> out[C][R] bf16
__global__ __launch_bounds__(256) void transpose_k(const void* __restrict__ in, bf16* __restrict__ out,
                                                   int R, int C, const int* __restrict__ flag) {
  bool f32 = *flag > FLAG_THRESH;
  __shared__ bf16 tile[32][33];
  int c0 = blockIdx.x * 32, r0 = blockIdx.y * 32;
  int tx = threadIdx.x, ty = threadIdx.y;
  #pragma unroll
  for (int i = 0; i < 4; i++)
    tile[ty + 8 * i][tx] = (bf16)ldx(in, (size_t)(r0 + ty + 8 * i) * C + c0 + tx, f32);
  __syncthreads();
  #pragma unroll
  for (int i = 0; i < 4; i++)
    out[(size_t)(c0 + ty + 8 * i) * R + r0 + tx] = tile[tx][ty + 8 * i];
}

// ---------------- layernorm over 1280 cols, one block per row, out bf16
__global__ __launch_bounds__(256) void ln_k(const void* __restrict__ x, const void* __restrict__ sc,
                                            const void* __restrict__ bi, bf16* __restrict__ out,
                                            const int* __restrict__ flag, int force_f32) {
  bool pf32 = *flag > FLAG_THRESH;
  bool xf32 = force_f32 || pf32;
  int row = blockIdx.x, t = threadIdx.x;
  float v[5];
  float s = 0.f, sq = 0.f;
  #pragma unroll
  for (int i = 0; i < 5; i++) {
    v[i] = ldx(x, (size_t)row * DIM + i * 256 + t, xf32);
    s += v[i]; sq += v[i] * v[i];
  }
  #pragma unroll
  for (int o = 32; o; o >>= 1) { s += __shfl_down(s, o); sq += __shfl_down(sq, o); }
  __shared__ float rs[4], rq[4];
  if ((t & 63) == 0) { rs[t >> 6] = s; rq[t >> 6] = sq; }
  __syncthreads();
  s = rs[0] + rs[1] + rs[2] + rs[3];
  sq = rq[0] + rq[1] + rq[2] + rq[3];
  float mean = s * (1.f / DIM);
  float var = sq * (1.f / DIM) - mean * mean;
  float rstd = rsqrtf(fmaxf(var, 0.f) + 1e-6f);
  #pragma unroll
  for (int i = 0; i < 5; i++) {
    int c = i * 256 + t;
    out[(size_t)row * DIM + c] = (bf16)((v[i] - mean) * rstd * ldx(sc, c, pf32) + ldx(bi, c, pf32));
  }
}

// ---------------- GEMM  C[M,N] = A[M,K] * Bt[N,K]^T   (128 x NT tile, BK=32, global_load_lds)
// NT=128: 4 waves each 64x64 (4x4 16-tiles). NT=64: 4 waves each 64x32 (4x2 16-tiles).
// MODE 0: out bf16 = acc+bias
// MODE 1: out f32  = acc+bias+res_ext(flag dtype)
// MODE 2: out bf16 = quickgelu(acc+bias)
template <int MODE, int NT>
__global__ __launch_bounds__(256) void gemm_bt(const bf16* __restrict__ A, const bf16* __restrict__ Bt,
                                               const void* __restrict__ bias, const void* __restrict__ res,
                                               void* __restrict__ out, int M, int N, int K,
                                               const int* __restrict__ flag) {
  bool pf32 = *flag > FLAG_THRESH;
  constexpr int TN = NT / 32;
  __shared__ bf16 As[128 * 32];
  __shared__ bf16 Bs[NT * 32];
  int tid = threadIdx.x;
  int lane = tid & 63, wv = tid >> 6;
  int quad = lane >> 4, l15 = lane & 15;
  int m0 = blockIdx.y * 128, n0 = blockIdx.x * NT;
  int wm = (wv & 1) * 64, wn = (wv >> 1) * (NT / 2);
  const bf16* Ag = A + (size_t)m0 * K;
  const bf16* Bg = Bt + (size_t)n0 * K;
  int r0 = tid >> 2, c0 = (tid & 3) * 8;
  int r1 = r0 + 64;
  f32x4 acc[4][TN];
  #pragma unroll
  for (int i = 0; i < 4; i++)
    #pragma unroll
    for (int j = 0; j < TN; j++) acc[i][j] = fz4();

  for (int k0 = 0; k0 < K; k0 += 32) {
    gl_lds16(Ag + (size_t)r0 * K + k0 + c0, &As[tid * 8]);
    gl_lds16(Ag + (size_t)r1 * K + k0 + c0, &As[(tid + 256) * 8]);
    gl_lds16(Bg + (size_t)r0 * K + k0 + c0, &Bs[tid * 8]);
    if constexpr (NT == 128) gl_lds16(Bg + (size_t)r1 * K + k0 + c0, &Bs[(tid + 256) * 8]);
    __syncthreads();
    bf16x8 af[4], bfr[TN];
    #pragma unroll
    for (int tm = 0; tm < 4; tm++) af[tm] = *(const bf16x8*)&As[(wm + tm * 16 + l15) * 32 + quad * 8];
    #pragma unroll
    for (int tn = 0; tn < TN; tn++) bfr[tn] = *(const bf16x8*)&Bs[(wn + tn * 16 + l15) * 32 + quad * 8];
    #pragma unroll
    for (int tm = 0; tm < 4; tm++)
      #pragma unroll
      for (int tn = 0; tn < TN; tn++)
        acc[tm][tn] = __builtin_amdgcn_mfma_f32_16x16x32_bf16(af[tm], bfr[tn], acc[tm][tn], 0, 0, 0);
    __syncthreads();
  }

  #pragma unroll
  for (int tm = 0; tm < 4; tm++) {
    #pragma unroll
    for (int tn = 0; tn < TN; tn++) {
      #pragma unroll
      for (int r = 0; r < 4; r++) {
        int row = m0 + wm + tm * 16 + quad * 4 + r;
        int col = n0 + wn + tn * 16 + l15;
        size_t idx = (size_t)row * N + col;
        float vv = acc[tm][tn][r] + ldx(bias, col, pf32);
        if constexpr (MODE == 0) ((bf16*)out)[idx] = (bf16)vv;
        if constexpr (MODE == 1) ((float*)out)[idx] = vv + ldx(res, idx, pf32);
        if constexpr (MODE == 2) ((bf16*)out)[idx] = (bf16)(vv / (1.f + expf(-1.702f * vv)));
      }
    }
  }
}

// ---------------- split-K GEMM: fp32 partials, 128x64 tile; grid (N/64, M/128, KS)
__global__ __launch_bounds__(256) void gemm_sk(const bf16* __restrict__ A, const bf16* __restrict__ Bt,
                                               float* __restrict__ part, int M, int N, int K, int chunk) {
  __shared__ bf16 As[128 * 32];
  __shared__ bf16 Bs[64 * 32];
  int tid = threadIdx.x;
  int lane = tid & 63, wv = tid >> 6;
  int quad = lane >> 4, l15 = lane & 15;
  int m0 = blockIdx.y * 128, n0 = blockIdx.x * 64;
  int wm = (wv & 1) * 64, wn = (wv >> 1) * 32;
  int kb = blockIdx.z * chunk;
  const bf16* Ag = A + (size_t)m0 * K;
  const bf16* Bg = Bt + (size_t)n0 * K;
  int r0 = tid >> 2, c0 = (tid & 3) * 8;
  int r1 = r0 + 64;
  f32x4 acc[4][2];
  #pragma unroll
  for (int i = 0; i < 4; i++)
    #pragma unroll
    for (int j = 0; j < 2; j++) acc[i][j] = fz4();

  for (int k0 = kb; k0 < kb + chunk; k0 += 32) {
    gl_lds16(Ag + (size_t)r0 * K + k0 + c0, &As[tid * 8]);
    gl_lds16(Ag + (size_t)r1 * K + k0 + c0, &As[(tid + 256) * 8]);
    gl_lds16(Bg + (size_t)r0 * K + k0 + c0, &Bs[tid * 8]);
    __syncthreads();
    bf16x8 af[4], bfr[2];
    #pragma unroll
    for (int tm = 0; tm < 4; tm++) af[tm] = *(const bf16x8*)&As[(wm + tm * 16 + l15) * 32 + quad * 8];
    #pragma unroll
    for (int tn = 0; tn < 2; tn++) bfr[tn] = *(const bf16x8*)&Bs[(wn + tn * 16 + l15) * 32 + quad * 8];
    #pragma unroll
    for (int tm = 0; tm < 4; tm++)
      #pragma unroll
      for (int tn = 0; tn < 2; tn++)
        acc[tm][tn] = __builtin_amdgcn_mfma_f32_16x16x32_bf16(af[tm], bfr[tn], acc[tm][tn], 0, 0, 0);
    __syncthreads();
  }

  float* po = part + (size_t)blockIdx.z * M * N;
  #pragma unroll
  for (int tm = 0; tm < 4; tm++) {
    #pragma unroll
    for (int tn = 0; tn < 2; tn++) {
      #pragma unroll
      for (int r = 0; r < 4; r++) {
        int row = m0 + wm + tm * 16 + quad * 4 + r;
        int col = n0 + wn + tn * 16 + l15;
        po[(size_t)row * N + col] = acc[tm][tn][r];
      }
    }
  }
}

// ---------------- split-K reduce: out = p0 + p1 + bias[col] + res (all fp32 except bias per flag)
__global__ __launch_bounds__(256) void reduce2_k(const float* __restrict__ p0, const float* __restrict__ p1,
                                                 const void* __restrict__ bias, const float* __restrict__ res,
                                                 float* __restrict__ out, int NCOL,
                                                 const int* __restrict__ flag) {
  bool pf32 = *flag > FLAG_THRESH;
  size_t i = ((size_t)blockIdx.x * 256 + threadIdx.x) * 4;
  int col = (int)(i % NCOL);
  float4 a = *(const float4*)&p0[i];
  float4 b = *(const float4*)&p1[i];
  float4 r = *(const float4*)&res[i];
  float4 o;
  o.x = a.x + b.x + r.x + ldx(bias, col + 0, pf32);
  o.y = a.y + b.y + r.y + ldx(bias, col + 1, pf32);
  o.z = a.z + b.z + r.z + ldx(bias, col + 2, pf32);
  o.w = a.w + b.w + r.w + ldx(bias, col + 3, pf32);
  *(float4*)&out[i] = o;
}

// ---------------- RoPE IN-PLACE on qkv [seq][3840]; q scaled by 1/sqrt(80); v untouched
__global__ __launch_bounds__(256) void rope_k(bf16* __restrict__ qkv, const void* __restrict__ rot,
                                              const int* __restrict__ flag) {
  bool pf32 = *flag > FLAG_THRESH;
  int idx = blockIdx.x * 256 + threadIdx.x;
  int d = idx % 40;
  int t = idx / 40;
  int head = t & 15;
  int seq = t >> 4;
  float f1 = ldx(rot, (size_t)seq * 40 + (d >> 1), pf32);
  float f2 = ldx(rot, (size_t)seq * 40 + (d >> 1) + 20, pf32);
  float c1 = cosf(f1), s1 = sinf(f1), c2 = cosf(f2), s2 = sinf(f2);
  const float scq = 0.11180339887498949f;
  size_t base = (size_t)seq * (3 * DIM) + head * HD + d;
  float x1 = (float)qkv[base], x2 = (float)qkv[base + 40];
  qkv[base] = (bf16)((x1 * c1 - x2 * s1) * scq);
  qkv[base + 40] = (bf16)((x2 * c2 + x1 * s2) * scq);
  x1 = (float)qkv[base + DIM]; x2 = (float)qkv[base + DIM + 40];
  qkv[base + DIM] = (bf16)(x1 * c1 - x2 * s1);
  qkv[base + DIM + 40] = (bf16)(x2 * c2 + x1 * s2);
}

// ---------------- MFMA flash attention: one block per (q-tile 64, head, segment)
__global__ __launch_bounds__(256) void attn_k(const bf16* __restrict__ qkv, const int* __restrict__ cu,
                                              bf16* __restrict__ out) {
  __shared__ bf16 Qs[64 * 96];
  __shared__ bf16 Ks[64 * 96];
  __shared__ bf16 Vt[80 * 64];
  __shared__ bf16 Ps[4][16 * 64];
  int tid = threadIdx.x, lane = tid & 63, wv = tid >> 6;
  int quad = lane >> 4, l15 = lane & 15;
  int qt = blockIdx.x, head = blockIdx.y, seg = blockIdx.z;
  int s0 = cu[seg], s1 = cu[seg + 1];
  int q0 = s0 + qt * 64;
  if (q0 >= s1) return;
  const bf16* qh = qkv + head * HD;
  const bf16* kh = qkv + DIM + head * HD;
  const bf16* vh = qkv + 2 * DIM + head * HD;
  const int RS = 3 * DIM;
  uint4 z4; z4.x = 0; z4.y = 0; z4.z = 0; z4.w = 0;
  for (int i = tid; i < 128; i += 256) {
    int r = i >> 1, c = i & 1;
    *(uint4*)&Qs[r * 96 + 80 + c * 8] = z4;
    *(uint4*)&Ks[r * 96 + 80 + c * 8] = z4;
  }
  for (int i = tid; i < 640; i += 256) {
    int r = i / 10, c = i % 10;
    *(bf16x8*)&Qs[r * 96 + c * 8] = *(const bf16x8*)&qh[(size_t)(q0 + r) * RS + c * 8];
  }
  float m_r[4], l_r[4];
  f32x4 oacc[5];
  #pragma unroll
  for (int r = 0; r < 4; r++) { m_r[r] = -1e30f; l_r[r] = 0.f; }
  #pragma unroll
  for (int nt = 0; nt < 5; nt++) oacc[nt] = fz4();

  for (int kt = s0; kt < s1; kt += 64) {
    __syncthreads();
    for (int i = tid; i < 640; i += 256) {
      int r = i / 10, c = i % 10;
      *(bf16x8*)&Ks[r * 96 + c * 8] = *(const bf16x8*)&kh[(size_t)(kt + r) * RS + c * 8];
      bf16x8 vv = *(const bf16x8*)&vh[(size_t)(kt + r) * RS + c * 8];
      #pragma unroll
      for (int j = 0; j < 8; j++) Vt[(c * 8 + j) * 64 + r] = vv[j];
    }
    __syncthreads();
    f32x4 sacc[4];
    #pragma unroll
    for (int j = 0; j < 4; j++) sacc[j] = fz4();
    #pragma unroll
    for (int ks = 0; ks < 3; ks++) {
      bf16x8 aq = *(const bf16x8*)&Qs[(wv * 16 + l15) * 96 + ks * 32 + quad * 8];
      #pragma unroll
      for (int j = 0; j < 4; j++) {
        bf16x8 bk = *(const bf16x8*)&Ks[(j * 16 + l15) * 96 + ks * 32 + quad * 8];
        sacc[j] = __builtin_amdgcn_mfma_f32_16x16x32_bf16(aq, bk, sacc[j], 0, 0, 0);
      }
    }
    #pragma unroll
    for (int r = 0; r < 4; r++) {
      float mx = fmaxf(fmaxf(sacc[0][r], sacc[1][r]), fmaxf(sacc[2][r], sacc[3][r]));
      #pragma unroll
      for (int o = 8; o; o >>= 1) mx = fmaxf(mx, __shfl_xor(mx, o));
      float mnew = fmaxf(m_r[r], mx);
      float alpha = expf(m_r[r] - mnew);
      float psum = 0.f;
      #pragma unroll
      for (int j = 0; j < 4; j++) {
        float p = expf(sacc[j][r] - mnew);
        psum += p;
        Ps[wv][(quad * 4 + r) * 64 + j * 16 + l15] = (bf16)p;
      }
      #pragma unroll
      for (int o = 8; o; o >>= 1) psum += __shfl_xor(psum, o);
      l_r[r] = l_r[r] * alpha + psum;
      m_r[r] = mnew;
      #pragma unroll
      for (int nt = 0; nt < 5; nt++) oacc[nt][r] *= alpha;
    }
    __syncthreads();
    #pragma unroll
    for (int ks = 0; ks < 2; ks++) {
      bf16x8 ap = *(const bf16x8*)&Ps[wv][l15 * 64 + ks * 32 + quad * 8];
      #pragma unroll
      for (int nt = 0; nt < 5; nt++) {
        bf16x8 bv = *(const bf16x8*)&Vt[(nt * 16 + l15) * 64 + ks * 32 + quad * 8];
        oacc[nt] = __builtin_amdgcn_mfma_f32_16x16x32_bf16(ap, bv, oacc[nt], 0, 0, 0);
      }
    }
  }
  #pragma unroll
  for (int nt = 0; nt < 5; nt++) {
    #pragma unroll
    for (int r = 0; r < 4; r++) {
      int row = q0 + wv * 16 + quad * 4 + r;
      int d = nt * 16 + l15;
      out[(size_t)row * DIM + head * HD + d] = (bf16)(oacc[nt][r] / l_r[r]);
    }
  }
}

// ---------------- workspace layout (max 154.7 MB; ws_size proven >= 186 MB in rounds 1-3)
// PART (split-K partials, 2 x 20.97 MB = 41.94 MB) aliases QKV+AO exactly (both dead by fc2)
#define FLAG_OFF 0UL
#define QKVT_OFF 256UL
#define PROJT_OFF 9830656UL
#define FC1T_OFF 13107456UL
#define FC2T_OFF 26214656UL
#define LN_OFF 39321856UL
#define QKV_OFF 49807616UL
#define PART_OFF 49807616UL
#define AO_OFF 81264896UL
#define H1_OFF 91750656UL
#define FC1O_OFF 112722176UL

extern "C" void kernel_launch(void* const* d_in, const int* in_sizes, int n_in,
                              void* d_out, int out_size, void* d_ws, size_t ws_size,
                              hipStream_t stream) {
  const void* hidden = d_in[0];
  const void* rot    = d_in[1];
  const int*  cu     = (const int*)d_in[2];
  const void* w_qkv  = d_in[3];
  const void* b_qkv  = d_in[4];
  const void* w_proj = d_in[5];
  const void* b_proj = d_in[6];
  const void* w_fc1  = d_in[7];
  const void* b_fc1  = d_in[8];
  const void* w_fc2  = d_in[9];
  const void* b_fc2  = d_in[10];
  const void* ln1s   = d_in[11];
  const void* ln1b   = d_in[12];
  const void* ln2s   = d_in[13];
  const void* ln2b   = d_in[14];

  char* ws = (char*)d_ws;
  int* flag   = (int*)(ws + FLAG_OFF);
  bf16* qkvT  = (bf16*)(ws + QKVT_OFF);
  bf16* projT = (bf16*)(ws + PROJT_OFF);
  bf16* fc1T  = (bf16*)(ws + FC1T_OFF);
  bf16* fc2T  = (bf16*)(ws + FC2T_OFF);
  bf16* ln_bf = (bf16*)(ws + LN_OFF);
  bf16* qkv   = (bf16*)(ws + QKV_OFF);
  float* part = (float*)(ws + PART_OFF);
  bf16* ao    = (bf16*)(ws + AO_OFF);
  float* h1   = (float*)(ws + H1_OFF);
  bf16* fc1o  = (bf16*)(ws + FC1O_OFF);

  zero_flag_k<<<1, 1, 0, stream>>>(flag);
  sniff_k<<<256, 256, 0, stream>>>((const unsigned short*)hidden, SEQ * DIM, flag);

  dim3 tb(32, 8);
  transpose_k<<<dim3(120, 40), tb, 0, stream>>>(w_qkv, qkvT, 1280, 3840, flag);
  transpose_k<<<dim3(40, 40), tb, 0, stream>>>(w_proj, projT, 1280, 1280, flag);
  transpose_k<<<dim3(160, 40), tb, 0, stream>>>(w_fc1, fc1T, 1280, 5120, flag);
  transpose_k<<<dim3(40, 160), tb, 0, stream>>>(w_fc2, fc2T, 5120, 1280, flag);

  ln_k<<<SEQ, 256, 0, stream>>>(hidden, ln1s, ln1b, ln_bf, flag, 0);
  gemm_bt<0, 128><<<dim3(30, 32), 256, 0, stream>>>(ln_bf, qkvT, b_qkv, nullptr, qkv, SEQ, 3 * DIM, DIM, flag);
  rope_k<<<10240, 256, 0, stream>>>(qkv, rot, flag);
  attn_k<<<dim3(16, NH, 4), 256, 0, stream>>>(qkv, cu, ao);
  gemm_bt<1, 64><<<dim3(20, 32), 256, 0, stream>>>(ao, projT, b_proj, hidden, h1, SEQ, DIM, DIM, flag);
  ln_k<<<SEQ, 256, 0, stream>>>(h1, ln2s, ln2b, ln_bf, flag, 1);
  gemm_bt<2, 128><<<dim3(40, 32), 256, 0, stream>>>(ln_bf, fc1T, b_fc1, nullptr, fc1o, SEQ, HIDDEN, DIM, flag);
  // fc2: split-K=2 (chunk 2560), 128x64 tiles -> 1280 blocks, then reduce with bias+residual
  gemm_sk<<<dim3(20, 32, 2), 256, 0, stream>>>(fc1o, fc2T, part, SEQ, DIM, HIDDEN, HIDDEN / 2);
  reduce2_k<<<SEQ * DIM / 1024, 256, 0, stream>>>(part, part + (size_t)SEQ * DIM, b_fc2, h1,
                                                  (float*)d_out, DIM, flag);
}